// Round 3
// baseline (172.792 us; speedup 1.0000x reference)
//
#include <hip/hip_runtime.h>

#define BROWS 524288
#define KBINS 64
#define GRID1 2048
// rows per block per outer iteration: 4 waves * 8 rows = 32 -> 8 iterations
#define ITERS (BROWS / (GRID1 * 32))

__global__ __launch_bounds__(256) void surv_fused(
    const float* __restrict__ inp, const float* __restrict__ yv,
    const int* __restrict__ ev, float* __restrict__ out,
    float* __restrict__ partials, unsigned* __restrict__ counter)
{
  const int tid  = threadIdx.x;
  const int lane = tid & 63;
  const int wave = tid >> 6;   // 0..3
  const int sub  = lane >> 4;  // row within 4-row group
  const int l16  = lane & 15;  // lane within row group

  const float A   = 2.8853900817779268f;   // 2*log2(e)  (logit scale in log2 domain)
  const float M2  = 0.28853900817779268f;  // 0.2*log2(e) (margin*scale in log2 domain)
  const float S0  = 0.018315638888734179f; // exp(-4)
  const float IS0 = 54.598150033144236f;   // exp(+4)
  const float LN2 = 0.6931471805599453f;

  float* cnt = out + 1;  // count[B,K] starts after the scalar loss
  float acc = 0.f;

  for (int it = 0; it < ITERS; ++it) {
    const int base = (it * GRID1 + blockIdx.x) * 32 + wave * 8;
    #pragma unroll
    for (int h = 0; h < 2; ++h) {
      const int row  = base + h * 4 + sub;
      const float y = yv[row];
      const int   e = ev[row];
      const int   b = (int)y;
      const bool valid = (y >= 0.f) && (y < 64.f);
      const int b_eff = valid ? b : 127;              // sentinel: c==0 everywhere
      const int hi    = (e != 0) ? b_eff : 63;        // count = [b_eff, hi]
      const bool all1 = (e == 0) && (b_eff == 0);     // count all-ones -> min==1

      const float4 x = *reinterpret_cast<const float4*>(
          inp + (size_t)row * KBINS + l16 * 4);
      const float xa[4] = {x.x, x.y, x.z, x.w};

      float correct = 0.f, fev = 0.f, fcs = 0.f;
      #pragma unroll
      for (int j = 0; j < 4; ++j) {
        const int bin = l16 * 4 + j;
        const bool c = (bin >= b_eff) && (bin <= hi);
        const float mm = (c && !all1) ? 0.f : M2;      // margin where count==min
        const float t  = fmaf(xa[j], A, mm);           // log2-domain logit
        const float pen = __builtin_amdgcn_exp2f(t);   // exp(+logit)
        const float pe  = __builtin_amdgcn_exp2f(-t);  // exp(-logit)
        correct += c ? pe  : 0.f;
        fcs     += c ? 0.f : pe;
        fev     += c ? 0.f : pen;
      }

      // count stores: normal cached stores (L2 write-allocate merges the
      // 4B-misaligned 64B chunks). bin = j*16 + l16 -> each instruction
      // writes 4 rows x 64B contiguous chunks. No nt (round-2 regression).
      {
        float* crow = cnt + (size_t)row * KBINS;
        #pragma unroll
        for (int j = 0; j < 4; ++j) {
          const int bin = j * 16 + l16;
          crow[bin] = (bin >= b_eff && bin <= hi) ? 1.f : 0.f;
        }
      }

      #pragma unroll
      for (int m = 1; m < 16; m <<= 1) {
        correct += __shfl_xor(correct, m, 64);
        fev     += __shfl_xor(fev, m, 64);
        fcs     += __shfl_xor(fcs, m, 64);
      }

      // sum(count)==1  <=>  valid && (event || b==K-1)
      const bool is_event = valid && (e != 0 || b == KBINS - 1);
      const float lev = (__builtin_amdgcn_logf(correct + S0) +
                         __builtin_amdgcn_logf(fev + S0)) * LN2;
      const float lcs = __builtin_amdgcn_logf(
                            fmaf(fcs, IS0, fmaf(correct, fcs, 1.f))) * LN2;
      if (l16 == 0) acc += is_event ? lev : lcs;
    }
  }

  // block reduction: acc nonzero at lanes {0,16,32,48}
  acc += __shfl_xor(acc, 16, 64);
  acc += __shfl_xor(acc, 32, 64);
  __shared__ float sm[4];
  __shared__ int amLast;
  if (lane == 0) sm[wave] = acc;
  __syncthreads();
  if (tid == 0) {
    partials[blockIdx.x] = (sm[0] + sm[1]) + (sm[2] + sm[3]);
    __threadfence();                       // release: partial visible device-wide
    unsigned old = atomicAdd(counter, 1u);
    amLast = (old == GRID1 - 1);
  }
  __syncthreads();
  if (amLast) {
    __threadfence();                       // acquire
    float s = 0.f;
    for (int i = tid; i < GRID1; i += 256)
      s += __hip_atomic_load(&partials[i], __ATOMIC_RELAXED,
                             __HIP_MEMORY_SCOPE_AGENT);
    #pragma unroll
    for (int m = 1; m < 64; m <<= 1) s += __shfl_xor(s, m, 64);
    __shared__ float sm2[4];
    if (lane == 0) sm2[wave] = s;
    __syncthreads();
    if (tid == 0) out[0] = ((sm2[0] + sm2[1]) + (sm2[2] + sm2[3])) *
                           (1.0f / (float)BROWS);
  }
}

extern "C" void kernel_launch(void* const* d_in, const int* in_sizes, int n_in,
                              void* d_out, int out_size, void* d_ws, size_t ws_size,
                              hipStream_t stream) {
  const float* inp = (const float*)d_in[0];
  const float* y   = (const float*)d_in[1];
  const int*   e   = (const int*)d_in[2];
  float* out      = (float*)d_out;
  float* partials = (float*)d_ws;                          // GRID1 floats
  unsigned* counter = (unsigned*)((char*)d_ws + 8192);     // after partials

  hipMemsetAsync(counter, 0, sizeof(unsigned), stream);
  surv_fused<<<GRID1, 256, 0, stream>>>(inp, y, e, out, partials, counter);
}

// Round 4
// 62.279 us; speedup vs baseline: 2.7745x; 2.7745x over previous
//
#include <hip/hip_runtime.h>

#define BROWS 524288
#define KBINS 64
#define GRID1 2048
// rows per block per outer iteration: 4 waves * 8 rows = 32 -> 8 iterations
#define ITERS (BROWS / (GRID1 * 32))

__global__ __launch_bounds__(256) void surv_main(
    const float* __restrict__ inp, const float* __restrict__ yv,
    const int* __restrict__ ev, float* __restrict__ out,
    float* __restrict__ partials)
{
  const int tid  = threadIdx.x;
  const int lane = tid & 63;
  const int wave = tid >> 6;   // 0..3
  const int sub  = lane >> 4;  // row within 4-row group
  const int l16  = lane & 15;  // lane within row group

  const float A   = 2.8853900817779268f;   // 2*log2(e)  (logit scale in log2 domain)
  const float M2  = 0.28853900817779268f;  // 0.2*log2(e) (margin*scale in log2 domain)
  const float S0  = 0.018315638888734179f; // exp(-4)
  const float IS0 = 54.598150033144236f;   // exp(+4)
  const float LN2 = 0.6931471805599453f;

  float* cnt = out + 1;  // count[B,K] starts after the scalar loss
  float acc = 0.f;

  for (int it = 0; it < ITERS; ++it) {
    const int base = (it * GRID1 + blockIdx.x) * 32 + wave * 8;
    #pragma unroll
    for (int h = 0; h < 2; ++h) {
      const int row  = base + h * 4 + sub;
      const float y = yv[row];
      const int   e = ev[row];
      const int   b = (int)y;
      const bool valid = (y >= 0.f) && (y < 64.f);
      const int b_eff = valid ? b : 127;              // sentinel: c==0 everywhere
      const int hi    = (e != 0) ? b_eff : 63;        // count = [b_eff, hi]
      const bool all1 = (e == 0) && (b_eff == 0);     // count all-ones -> min==1

      const float4 x = *reinterpret_cast<const float4*>(
          inp + (size_t)row * KBINS + l16 * 4);
      const float xa[4] = {x.x, x.y, x.z, x.w};

      float correct = 0.f, fev = 0.f, fcs = 0.f;
      #pragma unroll
      for (int j = 0; j < 4; ++j) {
        const int bin = l16 * 4 + j;
        const bool c = (bin >= b_eff) && (bin <= hi);
        const float mm = (c && !all1) ? 0.f : M2;      // margin where count==min
        const float t  = fmaf(xa[j], A, mm);           // log2-domain logit
        const float pen = __builtin_amdgcn_exp2f(t);   // exp(+logit)
        const float pe  = __builtin_amdgcn_exp2f(-t);  // exp(-logit)
        correct += c ? pe  : 0.f;
        fcs     += c ? 0.f : pe;
        fev     += c ? 0.f : pen;
      }

      // count stores: normal cached stores (L2 write-allocate merges the
      // 4B-misaligned 64B chunks). bin = j*16 + l16 -> each instruction
      // writes 4 rows x 64B contiguous chunks.
      {
        float* crow = cnt + (size_t)row * KBINS;
        #pragma unroll
        for (int j = 0; j < 4; ++j) {
          const int bin = j * 16 + l16;
          crow[bin] = (bin >= b_eff && bin <= hi) ? 1.f : 0.f;
        }
      }

      #pragma unroll
      for (int m = 1; m < 16; m <<= 1) {
        correct += __shfl_xor(correct, m, 64);
        fev     += __shfl_xor(fev, m, 64);
        fcs     += __shfl_xor(fcs, m, 64);
      }

      // sum(count)==1  <=>  valid && (event || b==K-1)
      const bool is_event = valid && (e != 0 || b == KBINS - 1);
      const float lev = (__builtin_amdgcn_logf(correct + S0) +
                         __builtin_amdgcn_logf(fev + S0)) * LN2;
      const float lcs = __builtin_amdgcn_logf(
                            fmaf(fcs, IS0, fmaf(correct, fcs, 1.f))) * LN2;
      if (l16 == 0) acc += is_event ? lev : lcs;
    }
  }

  // block reduction: acc nonzero at lanes {0,16,32,48}
  acc += __shfl_xor(acc, 16, 64);
  acc += __shfl_xor(acc, 32, 64);
  __shared__ float sm[4];
  if (lane == 0) sm[wave] = acc;
  __syncthreads();
  if (tid == 0) partials[blockIdx.x] = (sm[0] + sm[1]) + (sm[2] + sm[3]);
}

__global__ __launch_bounds__(256) void surv_reduce(
    const float* __restrict__ partials, float* __restrict__ out)
{
  __shared__ float sm[256];
  float s = 0.f;
  for (int i = threadIdx.x; i < GRID1; i += 256) s += partials[i];
  sm[threadIdx.x] = s;
  __syncthreads();
  for (int o = 128; o > 0; o >>= 1) {
    if (threadIdx.x < o) sm[threadIdx.x] += sm[threadIdx.x + o];
    __syncthreads();
  }
  if (threadIdx.x == 0) out[0] = sm[0] * (1.0f / (float)BROWS);
}

extern "C" void kernel_launch(void* const* d_in, const int* in_sizes, int n_in,
                              void* d_out, int out_size, void* d_ws, size_t ws_size,
                              hipStream_t stream) {
  const float* inp = (const float*)d_in[0];
  const float* y   = (const float*)d_in[1];
  const int*   e   = (const int*)d_in[2];
  float* out      = (float*)d_out;
  float* partials = (float*)d_ws;   // GRID1 floats

  surv_main<<<GRID1, 256, 0, stream>>>(inp, y, e, out, partials);
  surv_reduce<<<1, 256, 0, stream>>>(partials, out);
}

// Round 5
// 53.847 us; speedup vs baseline: 3.2089x; 1.1566x over previous
//
#include <hip/hip_runtime.h>

#define BROWS 524288
#define KBINS 64
#define GRID1 2048
// rows per block per outer iteration: 4 waves * 8 rows = 32 -> 8 iterations
#define ITERS (BROWS / (GRID1 * 32))

typedef float v4f __attribute__((ext_vector_type(4)));
// reduced-alignment vector: count rows start at d_out+4 (only 4B aligned).
// gfx9+ supports unaligned global multi-dword -> global_store_dwordx4.
typedef v4f v4f_u __attribute__((aligned(4)));

__global__ __launch_bounds__(256) void surv_main(
    const float* __restrict__ inp, const float* __restrict__ yv,
    const int* __restrict__ ev, float* __restrict__ out,
    float* __restrict__ partials)
{
  const int tid  = threadIdx.x;
  const int lane = tid & 63;
  const int wave = tid >> 6;   // 0..3
  const int sub  = lane >> 4;  // row within 4-row group
  const int l16  = lane & 15;  // lane within row group

  const float A   = 2.8853900817779268f;   // 2*log2(e)  (logit scale, log2 domain)
  const float M2  = 0.28853900817779268f;  // 0.2*log2(e) (margin*scale, log2 domain)
  const float S0  = 0.018315638888734179f; // exp(-4)
  const float IS0 = 54.598150033144236f;   // exp(+4)
  const float LN2 = 0.6931471805599453f;

  float* cnt = out + 1;  // count[B,K] starts after the scalar loss
  float acc = 0.f;

  for (int it = 0; it < ITERS; ++it) {
    const int base = (it * GRID1 + blockIdx.x) * 32 + wave * 8;
    const int row0 = base + sub;
    const int row1 = base + 4 + sub;

    // hoist both rows' loads -> 2-deep load pipeline
    const float y0 = yv[row0];
    const float y1 = yv[row1];
    const int   e0 = ev[row0];
    const int   e1 = ev[row1];
    const float4 x0 = *reinterpret_cast<const float4*>(
        inp + (size_t)row0 * KBINS + l16 * 4);
    const float4 x1 = *reinterpret_cast<const float4*>(
        inp + (size_t)row1 * KBINS + l16 * 4);

    #pragma unroll
    for (int h = 0; h < 2; ++h) {
      const int   row = h ? row1 : row0;
      const float y   = h ? y1 : y0;
      const int   e   = h ? e1 : e0;
      const float4 x  = h ? x1 : x0;
      const int   b = (int)y;
      const bool valid = (y >= 0.f) && (y < 64.f);
      const int b_eff = valid ? b : 127;              // sentinel: c==0 everywhere
      const int hi    = (e != 0) ? b_eff : 63;        // count = [b_eff, hi]
      const bool all1 = (e == 0) && (b_eff == 0);     // count all-ones -> min==1
      const float m_in = all1 ? M2 : 0.f;             // margin on count==1 bins

      const float xa[4] = {x.x, x.y, x.z, x.w};
      float correct = 0.f, fev = 0.f, fcs = 0.f;
      v4f cv;
      #pragma unroll
      for (int j = 0; j < 4; ++j) {
        const int bin = l16 * 4 + j;
        const bool c = (bin >= b_eff) && (bin <= hi);
        const float mm = c ? m_in : M2;
        const float t  = fmaf(xa[j], A, mm);           // log2-domain logit
        const float pen = __builtin_amdgcn_exp2f(t);   // exp(+logit)
        const float pe  = __builtin_amdgcn_exp2f(-t);  // exp(-logit)
        correct += c ? pe  : 0.f;
        fcs     += c ? 0.f : pe;
        fev     += c ? 0.f : pen;
        cv[j] = c ? 1.f : 0.f;
      }

      // single 16B (4B-aligned) store per lane covers this lane's 4 bins
      *reinterpret_cast<v4f_u*>(cnt + (size_t)row * KBINS + l16 * 4) = cv;

      #pragma unroll
      for (int m = 1; m < 16; m <<= 1) {
        correct += __shfl_xor(correct, m, 64);
        fev     += __shfl_xor(fev, m, 64);
        fcs     += __shfl_xor(fcs, m, 64);
      }

      // sum(count)==1  <=>  valid && (event || b==K-1)
      const bool is_event = valid && (e != 0 || b == KBINS - 1);
      const float lev = (__builtin_amdgcn_logf(correct + S0) +
                         __builtin_amdgcn_logf(fev + S0)) * LN2;
      const float lcs = __builtin_amdgcn_logf(
                            fmaf(fcs, IS0, fmaf(correct, fcs, 1.f))) * LN2;
      if (l16 == 0) acc += is_event ? lev : lcs;
    }
  }

  // block reduction: acc nonzero at lanes {0,16,32,48}
  acc += __shfl_xor(acc, 16, 64);
  acc += __shfl_xor(acc, 32, 64);
  __shared__ float sm[4];
  if (lane == 0) sm[wave] = acc;
  __syncthreads();
  if (tid == 0) partials[blockIdx.x] = (sm[0] + sm[1]) + (sm[2] + sm[3]);
}

__global__ __launch_bounds__(256) void surv_reduce(
    const float* __restrict__ partials, float* __restrict__ out)
{
  __shared__ float sm[256];
  float s = 0.f;
  for (int i = threadIdx.x; i < GRID1; i += 256) s += partials[i];
  sm[threadIdx.x] = s;
  __syncthreads();
  for (int o = 128; o > 0; o >>= 1) {
    if (threadIdx.x < o) sm[threadIdx.x] += sm[threadIdx.x + o];
    __syncthreads();
  }
  if (threadIdx.x == 0) out[0] = sm[0] * (1.0f / (float)BROWS);
}

extern "C" void kernel_launch(void* const* d_in, const int* in_sizes, int n_in,
                              void* d_out, int out_size, void* d_ws, size_t ws_size,
                              hipStream_t stream) {
  const float* inp = (const float*)d_in[0];
  const float* y   = (const float*)d_in[1];
  const int*   e   = (const int*)d_in[2];
  float* out      = (float*)d_out;
  float* partials = (float*)d_ws;   // GRID1 floats

  surv_main<<<GRID1, 256, 0, stream>>>(inp, y, e, out, partials);
  surv_reduce<<<1, 256, 0, stream>>>(partials, out);
}

// Round 6
// 52.215 us; speedup vs baseline: 3.3093x; 1.0313x over previous
//
#include <hip/hip_runtime.h>

#define BROWS 524288
#define KBINS 64
#define GRID1 2048
// rows per block per outer iteration: 4 waves * 8 rows = 32 -> 8 iterations
#define ITERS (BROWS / (GRID1 * 32))

typedef float v4f __attribute__((ext_vector_type(4)));

// Store scheme: count[B,K] lives at d_out+1 (4B misaligned). Instead of
// misaligned stores, each wave writes a fully-16B-aligned window of d_out:
// lane stores out[f .. f+3], f = row*64 + l16*4, covering count indices
// gidx = f-1+j (bins l16*4-1..l16*4+2 of own row; l16==0 j==0 is bin 63 of
// the PREVIOUS row). out[0] gets a garbage value, overwritten by surv_reduce.
// The final element out[B*64] (= count[B-1][63]) is stored by its owner lane.
__global__ __launch_bounds__(256) void surv_main(
    const float* __restrict__ inp, const float* __restrict__ yv,
    const int* __restrict__ ev, float* __restrict__ out,
    float* __restrict__ partials)
{
  const int tid  = threadIdx.x;
  const int lane = tid & 63;
  const int wave = tid >> 6;   // 0..3
  const int sub  = lane >> 4;  // row within 4-row group
  const int l16  = lane & 15;  // lane within row group

  const float A   = 2.8853900817779268f;   // 2*log2(e)  (logit scale, log2 domain)
  const float M2  = 0.28853900817779268f;  // 0.2*log2(e) (margin*scale, log2 domain)
  const float S0  = 0.018315638888734179f; // exp(-4)
  const float IS0 = 54.598150033144236f;   // exp(+4)
  const float LN2 = 0.6931471805599453f;

  float acc = 0.f;

  for (int it = 0; it < ITERS; ++it) {
    const int base = (it * GRID1 + blockIdx.x) * 32 + wave * 8;
    const int row0 = base + sub;
    const int row1 = base + 4 + sub;

    // hoist loads: both rows' y/e/x plus prev-row y/e (same cache lines)
    const int rp0 = row0 ? row0 - 1 : 0;   // clamp only hit at global row 0
    const int rp1 = row1 - 1;
    const float y0 = yv[row0], y1 = yv[row1];
    const int   e0 = ev[row0], e1 = ev[row1];
    const float yp0 = yv[rp0], yp1 = yv[rp1];
    const int   ep0 = ev[rp0], ep1 = ev[rp1];
    const float4 x0 = *reinterpret_cast<const float4*>(
        inp + (size_t)row0 * KBINS + l16 * 4);
    const float4 x1 = *reinterpret_cast<const float4*>(
        inp + (size_t)row1 * KBINS + l16 * 4);

    #pragma unroll
    for (int h = 0; h < 2; ++h) {
      const int   row = h ? row1 : row0;
      const float y   = h ? y1 : y0;
      const int   e   = h ? e1 : e0;
      const float yp  = h ? yp1 : yp0;
      const int   ep  = h ? ep1 : ep0;
      const float4 x  = h ? x1 : x0;

      const int   b = (int)y;
      const bool valid = (y >= 0.f) && (y < 64.f);
      const int b_eff = valid ? b : 127;              // sentinel: c==0 everywhere
      const int hi    = (e != 0) ? b_eff : 63;        // count = [b_eff, hi]
      const bool all1 = (e == 0) && (b_eff == 0);     // count all-ones -> min==1
      const float m_in = all1 ? M2 : 0.f;             // margin on count==1 bins

      // prev row's bin-63 count: 1 iff (e!=0 && b==63) or (e==0 && valid)
      const int   bp = (int)yp;
      const bool  vp = (yp >= 0.f) && (yp < 64.f);
      const float c63p = (ep != 0) ? ((vp && bp == 63) ? 1.f : 0.f)
                                   : (vp ? 1.f : 0.f);

      const float xa[4] = {x.x, x.y, x.z, x.w};
      float correct = 0.f, fev = 0.f, fcs = 0.f;
      float c[4];
      #pragma unroll
      for (int j = 0; j < 4; ++j) {
        const int bin = l16 * 4 + j;
        const bool cb = (bin >= b_eff) && (bin <= hi);
        const float mm = cb ? m_in : M2;
        const float t  = fmaf(xa[j], A, mm);           // log2-domain logit
        const float pen = __builtin_amdgcn_exp2f(t);   // exp(+logit)
        const float pe  = __builtin_amdgcn_exp2f(-t);  // exp(-logit)
        correct += cb ? pe  : 0.f;
        fcs     += cb ? 0.f : pe;
        fev     += cb ? 0.f : pen;
        c[j] = cb ? 1.f : 0.f;
      }

      // aligned shifted store: lane covers count bins l16*4-1 .. l16*4+2
      {
        const int binm1 = l16 * 4 - 1;                 // -1 for l16==0 (unused)
        const bool cm1 = (binm1 >= b_eff) && (binm1 <= hi);
        v4f cv;
        cv[0] = (l16 == 0) ? c63p : (cm1 ? 1.f : 0.f);
        cv[1] = c[0];
        cv[2] = c[1];
        cv[3] = c[2];
        *reinterpret_cast<v4f*>(out + (size_t)row * KBINS + l16 * 4) = cv;
        if (row == BROWS - 1 && l16 == 15)
          out[(size_t)BROWS * KBINS] = c[3];           // count[B-1][63]
      }

      #pragma unroll
      for (int m = 1; m < 16; m <<= 1) {
        correct += __shfl_xor(correct, m, 64);
        fev     += __shfl_xor(fev, m, 64);
        fcs     += __shfl_xor(fcs, m, 64);
      }

      // sum(count)==1  <=>  valid && (event || b==K-1)
      const bool is_event = valid && (e != 0 || b == KBINS - 1);
      const float lev = (__builtin_amdgcn_logf(correct + S0) +
                         __builtin_amdgcn_logf(fev + S0)) * LN2;
      const float lcs = __builtin_amdgcn_logf(
                            fmaf(fcs, IS0, fmaf(correct, fcs, 1.f))) * LN2;
      if (l16 == 0) acc += is_event ? lev : lcs;
    }
  }

  // block reduction: acc nonzero at lanes {0,16,32,48}
  acc += __shfl_xor(acc, 16, 64);
  acc += __shfl_xor(acc, 32, 64);
  __shared__ float sm[4];
  if (lane == 0) sm[wave] = acc;
  __syncthreads();
  if (tid == 0) partials[blockIdx.x] = (sm[0] + sm[1]) + (sm[2] + sm[3]);
}

__global__ __launch_bounds__(256) void surv_reduce(
    const float* __restrict__ partials, float* __restrict__ out)
{
  __shared__ float sm[256];
  float s = 0.f;
  for (int i = threadIdx.x; i < GRID1; i += 256) s += partials[i];
  sm[threadIdx.x] = s;
  __syncthreads();
  for (int o = 128; o > 0; o >>= 1) {
    if (threadIdx.x < o) sm[threadIdx.x] += sm[threadIdx.x + o];
    __syncthreads();
  }
  if (threadIdx.x == 0) out[0] = sm[0] * (1.0f / (float)BROWS);
}

extern "C" void kernel_launch(void* const* d_in, const int* in_sizes, int n_in,
                              void* d_out, int out_size, void* d_ws, size_t ws_size,
                              hipStream_t stream) {
  const float* inp = (const float*)d_in[0];
  const float* y   = (const float*)d_in[1];
  const int*   e   = (const int*)d_in[2];
  float* out      = (float*)d_out;
  float* partials = (float*)d_ws;   // GRID1 floats

  surv_main<<<GRID1, 256, 0, stream>>>(inp, y, e, out, partials);
  surv_reduce<<<1, 256, 0, stream>>>(partials, out);
}